// Round 7
// baseline (739.165 us; speedup 1.0000x reference)
//
#include <hip/hip_runtime.h>

#define N_PTS 300000
#define NPAD  300032   // multiple of 256
#define ZROW  N_PTS    // zeroed feature row used for missing neighbors

typedef _Float16 f16;
typedef _Float16 f16x8 __attribute__((ext_vector_type(8)));
typedef float    f32x4 __attribute__((ext_vector_type(4)));

__device__ __forceinline__ f16 f2h(float x) { return (f16)x; }

union u4f16 { uint4 u; f16x8 h; };

#define HEAD_BLOCKS (NPAD / 256)   // 1172
#define WP_BLOCKS   368            // 368*256 = 94208 weight elements

// ---------------------------------------------------------------------------
// head: fused feature-prep + bottleneck + weight transposes (unchanged R6).
// ---------------------------------------------------------------------------
__global__ __launch_bounds__(256) void k_head(
    const float* __restrict__ feat, const float* __restrict__ W2a,
    const float* __restrict__ s2a, const float* __restrict__ b2a,
    const float* __restrict__ W1, const float* __restrict__ W2b,
    const float* __restrict__ W3,
    f16* __restrict__ featf, f16* __restrict__ hf,
    f16* __restrict__ Wt1, f16* __restrict__ Wt2b, f16* __restrict__ Wt3)
{
    if (blockIdx.x >= HEAD_BLOCKS) {   // weight-transpose blocks
        int j = (blockIdx.x - HEAD_BLOCKS) * 256 + threadIdx.x;
        if (j < 36864) {                       // Wt1 [k][ch][cin]
            int k = j >> 12, rem = j & 4095, d = rem >> 6, c = rem & 63;
            Wt1[j] = f2h(W1[(k << 12) + (c << 6) + d]);
        } else if (j < 73728) {                // Wt3
            int jj = j - 36864;
            int k = jj >> 12, rem = jj & 4095, d = rem >> 6, c = rem & 63;
            Wt3[jj] = f2h(W3[(k << 12) + (c << 6) + d]);
        } else if (j < 73728 + 18432) {        // Wt2b [k][ch][c2]
            int jj = j - 73728;
            int k = jj >> 11, rem = jj & 2047, d = rem >> 5, c2 = rem & 31;
            Wt2b[jj] = f2h(W2b[k * 2048 + c2 * 64 + d]);
        }
        return;
    }

    int lane = threadIdx.x & 63, wave = threadIdx.x >> 6;
    int n0 = (blockIdx.x * 4 + wave) * 64;
    int ln = lane & 15, q = lane >> 4;

    f16x8 a[4][2];
#pragma unroll
    for (int mt = 0; mt < 4; mt++) {
        int n = n0 + mt * 16 + ln;
#pragma unroll
        for (int ks = 0; ks < 2; ks++) {
            u4f16 v;
            if (n < N_PTS) {
                const float* p = feat + (long)n * 64 + ks * 32 + q * 8;
                float4 lo = *(const float4*)p;
                float4 hi = *(const float4*)(p + 4);
                v.h[0] = f2h(lo.x); v.h[1] = f2h(lo.y);
                v.h[2] = f2h(lo.z); v.h[3] = f2h(lo.w);
                v.h[4] = f2h(hi.x); v.h[5] = f2h(hi.y);
                v.h[6] = f2h(hi.z); v.h[7] = f2h(hi.w);
            } else {
                v.u = make_uint4(0u, 0u, 0u, 0u);
            }
            a[mt][ks] = v.h;
            *(uint4*)(featf + (long)n * 64 + ks * 32 + q * 8) = v.u;
        }
    }

    f32x4 acc[4][2];
    for (int mt = 0; mt < 4; mt++) for (int nt = 0; nt < 2; nt++)
        acc[mt][nt] = (f32x4){0.f, 0.f, 0.f, 0.f};
#pragma unroll
    for (int ks = 0; ks < 2; ks++)
#pragma unroll
        for (int nt = 0; nt < 2; nt++) {
            f16x8 b;
#pragma unroll
            for (int j = 0; j < 8; j++)
                b[j] = f2h(W2a[(ks * 32 + q * 8 + j) * 32 + nt * 16 + ln]);
#pragma unroll
            for (int mt = 0; mt < 4; mt++)
                acc[mt][nt] = __builtin_amdgcn_mfma_f32_16x16x32_f16(a[mt][ks], b, acc[mt][nt], 0, 0, 0);
        }

#pragma unroll
    for (int nt = 0; nt < 2; nt++) {
        int ch = nt * 16 + ln;
        float s = s2a[ch], bb = b2a[ch];
#pragma unroll
        for (int mt = 0; mt < 4; mt++)
#pragma unroll
            for (int r = 0; r < 4; r++) {
                int n = n0 + mt * 16 + q * 4 + r;
                float v = (n < N_PTS) ? fmaxf(acc[mt][nt][r] * s + bb, 0.f) : 0.f;
                hf[(long)n * 32 + ch] = f2h(v);
            }
    }
}

// ---------------------------------------------------------------------------
// sparse-conv path, operand-swapped: A = weights (stationary in 288 VGPRs),
// B = gathered rows. K-loop vmem stream = gathers ONLY -> the compiler's
// in-order vmcnt waits give a TRUE depth-2.5 pipeline (ring of 3 taps).
// D layout [ch][pt]: each lane holds 4 contiguous ch for one pt.
// ---------------------------------------------------------------------------
template <int CIN>
__device__ __forceinline__ void fill_tap(
    uint4 (&slot)[4][CIN / 32], int idxk,
    const f16* __restrict__ src, int ln, int q)
{
#pragma unroll
    for (int pg = 0; pg < 4; pg++) {
        int rid = __builtin_amdgcn_ds_bpermute((pg * 16 + ln) * 4, idxk);
        const f16* p = src + (long)rid * CIN + q * 8;
#pragma unroll
        for (int ks = 0; ks < CIN / 32; ks++)
            slot[pg][ks] = *(const uint4*)(p + ks * 32);
    }
}

template <int CIN>
__device__ __forceinline__ void conv_path(
    const f16* __restrict__ src, const f16* __restrict__ Wt,
    const int* __restrict__ nbr,
    int lane, int n0,
    const float* __restrict__ bns, const float* __restrict__ bnb,
    f16* __restrict__ msf, int colBase, float* __restrict__ pooled)
{
    constexpr int KS = CIN / 32;
    int ln = lane & 15, q = lane >> 4;

    // all 9 taps' indices upfront; row = lane; missing/pad -> ZROW
    int idxf[9];
#pragma unroll
    for (int k = 0; k < 9; k++) {
        int nn = n0 + lane;
        int v = (nn < N_PTS) ? nbr[k * N_PTS + nn] : -1;
        idxf[k] = (v < 0) ? ZROW : v;
    }

    // stationary A-operand: all 9 taps' weights in registers
    f16x8 wfr[9][4][KS];
#pragma unroll
    for (int t = 0; t < 9; t++)
#pragma unroll
        for (int ct = 0; ct < 4; ct++)
#pragma unroll
            for (int ks = 0; ks < KS; ks++)
                wfr[t][ct][ks] = *(const f16x8*)(Wt + (t * 64 + ct * 16 + ln) * CIN + ks * 32 + q * 8);

    f32x4 acc[4][4];
    for (int ct = 0; ct < 4; ct++) for (int pg = 0; pg < 4; pg++)
        acc[ct][pg] = (f32x4){0.f, 0.f, 0.f, 0.f};

    uint4 ring[3][4][KS];
    fill_tap<CIN>(ring[0], idxf[0], src, ln, q);
    fill_tap<CIN>(ring[1], idxf[1], src, ln, q);
    fill_tap<CIN>(ring[2], idxf[2], src, ln, q);

#pragma unroll
    for (int k = 0; k < 9; k++) {
        const int s = k % 3;
#pragma unroll
        for (int ks = 0; ks < KS; ks++)
#pragma unroll
            for (int ct = 0; ct < 4; ct++)
#pragma unroll
                for (int pg = 0; pg < 4; pg++) {
                    u4f16 v; v.u = ring[s][pg][ks];
                    acc[ct][pg] = __builtin_amdgcn_mfma_f32_16x16x32_f16(
                        wfr[k][ct][ks], v.h, acc[ct][pg], 0, 0, 0);
                }
        if (k + 3 < 9) fill_tap<CIN>(ring[s], idxf[k + 3], src, ln, q);
    }

    // epilogue: BN+ReLU; lane holds ch = ct*16+q*4+r for pt = pg*16+ln
#pragma unroll
    for (int ct = 0; ct < 4; ct++) {
        f32x4 sv = *(const f32x4*)(bns + ct * 16 + q * 4);
        f32x4 bv = *(const f32x4*)(bnb + ct * 16 + q * 4);
        float rmax[4] = {0.f, 0.f, 0.f, 0.f};
#pragma unroll
        for (int pg = 0; pg < 4; pg++) {
            int pt = n0 + pg * 16 + ln;           // always < NPAD
            bool valid = pt < N_PTS;
            union { f16 h[4]; uint2 u2; } pk;
#pragma unroll
            for (int r = 0; r < 4; r++) {
                float v = fmaxf(acc[ct][pg][r] * sv[r] + bv[r], 0.f);
                pk.h[r] = f2h(v);
                if (valid) rmax[r] = fmaxf(rmax[r], v);
            }
            *(uint2*)(msf + (long)pt * 192 + colBase + ct * 16 + q * 4) = pk.u2;
        }
#pragma unroll
        for (int r = 0; r < 4; r++) {
            float m = rmax[r];
            m = fmaxf(m, __shfl_xor(m, 1));
            m = fmaxf(m, __shfl_xor(m, 2));
            m = fmaxf(m, __shfl_xor(m, 4));
            m = fmaxf(m, __shfl_xor(m, 8));
            if (ln == 0)
                atomicMax((int*)(pooled + colBase + ct * 16 + q * 4 + r), __float_as_int(m));
        }
    }
}

__global__ __launch_bounds__(256, 1) void k_conv(
    const f16* __restrict__ featf, const f16* __restrict__ hf,
    const f16* __restrict__ Wt1, const f16* __restrict__ Wt2b, const f16* __restrict__ Wt3,
    const int* __restrict__ nbr1, const int* __restrict__ nbr2,
    const float* __restrict__ bn1_s, const float* __restrict__ bn1_b,
    const float* __restrict__ bn2b_s, const float* __restrict__ bn2b_b,
    const float* __restrict__ bn3_s, const float* __restrict__ bn3_b,
    f16* __restrict__ msf, float* __restrict__ pooled)
{
    int lane = threadIdx.x & 63, wave = threadIdx.x >> 6;
    int u = blockIdx.x * 4 + wave;       // (64-pt tile, path) unit
    int tile = u / 3, path = u - tile * 3;
    int n0 = tile * 64;
    if (path == 0)
        conv_path<64>(featf, Wt1,  nbr1, lane, n0, bn1_s,  bn1_b,  msf, 0,   pooled);
    else if (path == 1)
        conv_path<32>(hf,    Wt2b, nbr1, lane, n0, bn2b_s, bn2b_b, msf, 64,  pooled);
    else
        conv_path<64>(featf, Wt3,  nbr2, lane, n0, bn3_s,  bn3_b,  msf, 128, pooled);
}

// ---------------------------------------------------------------------------
// attention MLP (1 block) + fold attn*Wf -> Wfst[d][j] fp16  (unchanged)
// ---------------------------------------------------------------------------
__global__ __launch_bounds__(256) void k_attn(
    const float* __restrict__ pooled,
    const float* __restrict__ A1w, const float* __restrict__ A1b,
    const float* __restrict__ A2w, const float* __restrict__ A2b,
    const float* __restrict__ Wf, f16* __restrict__ Wfst)
{
    __shared__ float sp[192], sa1[16], sattn[192];
    int t = threadIdx.x;
    if (t < 192) sp[t] = pooled[t];
    __syncthreads();
    if (t < 16) {
        float acc = A1b[t];
        for (int i = 0; i < 192; i++) acc += sp[i] * A1w[i * 16 + t];
        sa1[t] = fmaxf(acc, 0.f);
    }
    __syncthreads();
    if (t < 192) {
        float acc = A2b[t];
        for (int i = 0; i < 16; i++) acc += sa1[i] * A2w[i * 192 + t];
        sattn[t] = 1.f / (1.f + expf(-acc));
    }
    __syncthreads();
    for (int i = t; i < 192 * 64; i += 256) {
        int d = i / 192, j = i % 192;
        Wfst[i] = f2h(Wf[j * 64 + d] * sattn[j]);
    }
}

// ---------------------------------------------------------------------------
// fusion: out = relu(bnf( ms @ (attn*Wf) ))  fp32 out  (unchanged)
// ---------------------------------------------------------------------------
__global__ __launch_bounds__(256, 4) void k_fuse(
    const f16* __restrict__ msf, const f16* __restrict__ Wfst,
    const float* __restrict__ sf, const float* __restrict__ bf_,
    float* __restrict__ out)
{
    int lane = threadIdx.x & 63, wave = threadIdx.x >> 6;
    int n0 = (blockIdx.x * 4 + wave) * 32;
    int ln = lane & 15, q = lane >> 4;

    uint4 araw[6][2];
#pragma unroll
    for (int kt = 0; kt < 6; kt++)
#pragma unroll
        for (int mt = 0; mt < 2; mt++)
            araw[kt][mt] = *(const uint4*)(msf + (long)(n0 + mt * 16 + ln) * 192 + kt * 32 + q * 8);

    f32x4 acc[2][4];
    for (int mt = 0; mt < 2; mt++) for (int nt = 0; nt < 4; nt++)
        acc[mt][nt] = (f32x4){0.f, 0.f, 0.f, 0.f};

#pragma unroll
    for (int kt = 0; kt < 6; kt++)
#pragma unroll
        for (int nt = 0; nt < 4; nt++) {
            f16x8 b = *(const f16x8*)(Wfst + ((nt * 16 + ln) * 192 + kt * 32 + q * 8));
#pragma unroll
            for (int mt = 0; mt < 2; mt++) {
                u4f16 v; v.u = araw[kt][mt];
                acc[mt][nt] = __builtin_amdgcn_mfma_f32_16x16x32_f16(v.h, b, acc[mt][nt], 0, 0, 0);
            }
        }

#pragma unroll
    for (int nt = 0; nt < 4; nt++) {
        int ch = nt * 16 + ln;
        float s = sf[ch], bb = bf_[ch];
#pragma unroll
        for (int mt = 0; mt < 2; mt++)
#pragma unroll
            for (int r = 0; r < 4; r++) {
                int n = n0 + mt * 16 + q * 4 + r;
                if (n < N_PTS)
                    out[(long)n * 64 + ch] = fmaxf(acc[mt][nt][r] * s + bb, 0.f);
            }
    }
}

// ---------------------------------------------------------------------------
extern "C" void kernel_launch(void* const* d_in, const int* in_sizes, int n_in,
                              void* d_out, int out_size, void* d_ws, size_t ws_size,
                              hipStream_t stream)
{
    const float* features = (const float*)d_in[0];
    const float* W1     = (const float*)d_in[1];
    const float* bn1_s  = (const float*)d_in[2];
    const float* bn1_b  = (const float*)d_in[3];
    const float* W2a    = (const float*)d_in[4];
    const float* bn2a_s = (const float*)d_in[5];
    const float* bn2a_b = (const float*)d_in[6];
    const float* W2b    = (const float*)d_in[7];
    const float* bn2b_s = (const float*)d_in[8];
    const float* bn2b_b = (const float*)d_in[9];
    const float* W3     = (const float*)d_in[10];
    const float* bn3_s  = (const float*)d_in[11];
    const float* bn3_b  = (const float*)d_in[12];
    const float* A1w    = (const float*)d_in[13];
    const float* A1b    = (const float*)d_in[14];
    const float* A2w    = (const float*)d_in[15];
    const float* A2b    = (const float*)d_in[16];
    const float* Wf     = (const float*)d_in[17];
    const float* bnf_s  = (const float*)d_in[18];
    const float* bnf_b  = (const float*)d_in[19];
    const int*   nbr1   = (const int*)d_in[20];
    const int*   nbr2   = (const int*)d_in[21];

    char* ws = (char*)d_ws;
    size_t off = 0;
    f16* featf = (f16*)(ws + off); off += (size_t)NPAD * 64 * 2;
    f16* hf    = (f16*)(ws + off); off += (size_t)NPAD * 32 * 2;
    f16* msf   = (f16*)(ws + off); off += (size_t)NPAD * 192 * 2;
    f16* Wt1   = (f16*)(ws + off); off += 9 * 64 * 64 * 2;
    f16* Wt3   = (f16*)(ws + off); off += 9 * 64 * 64 * 2;
    f16* Wt2b  = (f16*)(ws + off); off += 9 * 32 * 64 * 2;
    f16* Wfst  = (f16*)(ws + off); off += 192 * 64 * 2;
    float* pooled = (float*)(ws + off); off += 256 * 4;

    hipMemsetAsync(pooled, 0, 192 * sizeof(float), stream);

    k_head<<<HEAD_BLOCKS + WP_BLOCKS, 256, 0, stream>>>(
        features, W2a, bn2a_s, bn2a_b, W1, W2b, W3,
        featf, hf, Wt1, Wt2b, Wt3);
    k_conv<<<(NPAD / 64) * 3 / 4, 256, 0, stream>>>(featf, hf, Wt1, Wt2b, Wt3, nbr1, nbr2,
                                           bn1_s, bn1_b, bn2b_s, bn2b_b, bn3_s, bn3_b,
                                           msf, pooled);
    k_attn<<<1, 256, 0, stream>>>(pooled, A1w, A1b, A2w, A2b, Wf, Wfst);
    k_fuse<<<NPAD / 128, 256, 0, stream>>>(msf, Wfst, bnf_s, bnf_b, (float*)d_out);
}